// Round 4
// baseline (663.839 us; speedup 1.0000x reference)
//
#include <hip/hip_runtime.h>

#define B 8
#define C 256
#define HW 18432          // 96*192
#define K 19
#define EPS_MEAN 1e-6f
#define EPS_COS 1e-8f
#define PAD 257           // LDS stride for means tables: bank=(k+c)%32

// ---------------- per-(b,k) pixel counts (72 blocks, global atomics) ----------------
__global__ __launch_bounds__(256) void k_counts(const int* __restrict__ target,
                                                int* __restrict__ counts) {
    __shared__ int hist[K * 256];
    __shared__ int red[K][4];
    const int tid = threadIdx.x, cx = blockIdx.x, b = blockIdx.y;
    for (int k = 0; k < K; ++k) hist[k * 256 + tid] = 0;
    const int4* t4 = (const int4*)(target + (size_t)b * HW + cx * 2048);
#pragma unroll
    for (int i = 0; i < 2; ++i) {
        int4 t = t4[i * 256 + tid];
        { unsigned k0 = (unsigned)t.x; bool ok = k0 < K; atomicAdd(&hist[(ok ? k0 : 0u) * 256 + tid], ok ? 1 : 0); }
        { unsigned k0 = (unsigned)t.y; bool ok = k0 < K; atomicAdd(&hist[(ok ? k0 : 0u) * 256 + tid], ok ? 1 : 0); }
        { unsigned k0 = (unsigned)t.z; bool ok = k0 < K; atomicAdd(&hist[(ok ? k0 : 0u) * 256 + tid], ok ? 1 : 0); }
        { unsigned k0 = (unsigned)t.w; bool ok = k0 < K; atomicAdd(&hist[(ok ? k0 : 0u) * 256 + tid], ok ? 1 : 0); }
    }
    const int wid = tid >> 6, lane = tid & 63;
    for (int k = 0; k < K; ++k) {
        int v = hist[k * 256 + tid];
        for (int off = 32; off; off >>= 1) v += __shfl_xor(v, off);
        if (lane == 0) red[k][wid] = v;
    }
    __syncthreads();
    if (tid < K) atomicAdd(&counts[b * K + tid], red[tid][0] + red[tid][1] + red[tid][2] + red[tid][3]);
}

// ---------------- per-(z,b,c) class sums — ds_add fire-and-forget ----------------
__global__ __launch_bounds__(256) void k_sums(const float* __restrict__ fS,
                                              const float* __restrict__ fT,
                                              const int* __restrict__ target,
                                              float* __restrict__ sums) {
    __shared__ float hist[K * 256];
    __shared__ float red[K][4];
    const int tid = threadIdx.x;
    const int c = blockIdx.x, b = blockIdx.y, z = blockIdx.z;
    const float* feat = z ? fT : fS;
    for (int k = 0; k < K; ++k) hist[k * 256 + tid] = 0.0f;
    const float4* f4 = (const float4*)(feat + (size_t)(b * C + c) * HW);
    const int4*   t4 = (const int4*)(target + (size_t)b * HW);
#pragma unroll 4
    for (int i = 0; i < HW / 1024; ++i) {
        float4 v = f4[i * 256 + tid];
        int4   t = t4[i * 256 + tid];
        { unsigned k0 = (unsigned)t.x; bool ok = k0 < K; atomicAdd(&hist[(ok ? k0 : 0u) * 256 + tid], ok ? v.x : 0.f); }
        { unsigned k0 = (unsigned)t.y; bool ok = k0 < K; atomicAdd(&hist[(ok ? k0 : 0u) * 256 + tid], ok ? v.y : 0.f); }
        { unsigned k0 = (unsigned)t.z; bool ok = k0 < K; atomicAdd(&hist[(ok ? k0 : 0u) * 256 + tid], ok ? v.z : 0.f); }
        { unsigned k0 = (unsigned)t.w; bool ok = k0 < K; atomicAdd(&hist[(ok ? k0 : 0u) * 256 + tid], ok ? v.w : 0.f); }
    }
    const int wid = tid >> 6, lane = tid & 63;
    for (int k = 0; k < K; ++k) {
        float v = hist[k * 256 + tid];
        for (int off = 32; off; off >>= 1) v += __shfl_xor(v, off);
        if (lane == 0) red[k][wid] = v;
    }
    __syncthreads();
    if (tid < K)
        sums[((size_t)(z * B + b) * K + tid) * C + c] =
            red[tid][0] + red[tid][1] + red[tid][2] + red[tid][3];
}

// ---------------- means + center norms ----------------
__global__ __launch_bounds__(256) void k_means(const float* __restrict__ sums,
                                               const int* __restrict__ counts,
                                               float* __restrict__ means,
                                               float* __restrict__ ny) {
    __shared__ float red0[4], red1[4];
    const int tid = threadIdx.x;
    const int bk = blockIdx.x;                        // b*K + k
    const float inv = 1.0f / ((float)counts[bk] + EPS_MEAN);
    const size_t i0 = (size_t)bk * C + tid;           // z = 0 (S)
    const size_t i1 = (size_t)(B * K + bk) * C + tid; // z = 1 (T)
    float m0 = sums[i0] * inv, m1 = sums[i1] * inv;
    means[i0] = m0; means[i1] = m1;
    float s0 = m0 * m0, s1 = m1 * m1;
    for (int off = 32; off; off >>= 1) {
        s0 += __shfl_xor(s0, off);
        s1 += __shfl_xor(s1, off);
    }
    const int wid = tid >> 6, lane = tid & 63;
    if (lane == 0) { red0[wid] = s0; red1[wid] = s1; }
    __syncthreads();
    if (tid == 0) ny[bk]         = sqrtf(red0[0] + red0[1] + red0[2] + red0[3]);
    if (tid == 1) ny[B * K + bk] = sqrtf(red1[0] + red1[1] + red1[2] + red1[3]);
}

// ---------------- per-pixel cosine sims + loss (wave = 16 px x 4 c-groups) ----------------
__global__ __launch_bounds__(512) void k_loss(const float* __restrict__ fS,
                                              const float* __restrict__ fT,
                                              const int* __restrict__ target,
                                              const float* __restrict__ means,
                                              const float* __restrict__ ny,
                                              float* __restrict__ loss_acc) {
    __shared__ float mS[K * PAD];
    __shared__ float mT[K * PAD];
    __shared__ float nys[2 * K];
    __shared__ float red[8];
    const int tid = threadIdx.x;
    const int b = blockIdx.y;
    for (int idx = tid; idx < K * C; idx += 512) {
        int k = idx >> 8, c = idx & 255;
        mS[k * PAD + c] = means[((size_t)b * K + k) * C + c];
        mT[k * PAD + c] = means[((size_t)(B * K + b * K + k)) * C + c];
    }
    if (tid < 2 * K)
        nys[tid] = ny[(tid < K) ? (b * K + tid) : (B * K + b * K + (tid - K))];
    __syncthreads();

    const int wid = tid >> 6, lane = tid & 63;
    const int pxl = lane & 15, cg = lane >> 4;        // 16 px x 4 channel-groups
    const int px = blockIdx.x * 128 + wid * 16 + pxl;
    const int k = target[(size_t)b * HW + px];
    const bool valid = (unsigned)k < (unsigned)K;
    const int kk = valid ? k : 0;
    const float* pS = fS + ((size_t)b * C + cg * 64) * HW + px;
    const float* pT = fT + ((size_t)b * C + cg * 64) * HW + px;
    const float* msrow = &mS[kk * PAD + cg * 64];
    const float* mtrow = &mT[kk * PAD + cg * 64];
    float dS = 0.f, qS = 0.f, dT = 0.f, qT = 0.f;
#pragma unroll 8
    for (int i = 0; i < 64; ++i) {
        float vS = pS[(size_t)i * HW];
        float vT = pT[(size_t)i * HW];
        dS += vS * msrow[i]; qS += vS * vS;
        dT += vT * mtrow[i]; qT += vT * vT;
    }
    // combine the 4 channel-groups (lanes pxl, pxl+16, pxl+32, pxl+48)
    dS += __shfl_xor(dS, 16); dS += __shfl_xor(dS, 32);
    qS += __shfl_xor(qS, 16); qS += __shfl_xor(qS, 32);
    dT += __shfl_xor(dT, 16); dT += __shfl_xor(dT, 32);
    qT += __shfl_xor(qT, 16); qT += __shfl_xor(qT, 32);
    float psS = dS / fmaxf(sqrtf(qS) * nys[kk], EPS_COS);
    float psT = dT / fmaxf(sqrtf(qT) * nys[K + kk], EPS_COS);
    float d = (valid && cg == 0) ? (psS - psT) : 0.0f;
    float v = d * d;
    for (int off = 32; off; off >>= 1) v += __shfl_xor(v, off);
    if (lane == 0) red[wid] = v;
    __syncthreads();
    if (tid == 0) {
        float s = 0.f;
        for (int w = 0; w < 8; ++w) s += red[w];
        atomicAdd(loss_acc, s);
    }
}

__global__ void k_final(const float* __restrict__ loss_acc, float* __restrict__ out) {
    out[0] = loss_acc[0] * (1.0f / (float)(B * HW));
}

extern "C" void kernel_launch(void* const* d_in, const int* in_sizes, int n_in,
                              void* d_out, int out_size, void* d_ws, size_t ws_size,
                              hipStream_t stream) {
    const float* fS     = (const float*)d_in[0];
    const float* fT     = (const float*)d_in[1];
    const int*   target = (const int*)d_in[2];
    float* out = (float*)d_out;
    char*  ws  = (char*)d_ws;

    // ws layout: [0] loss_acc(4) | [4] counts(608) | [1024] sums(311296)
    //            | [1024+311296] means(311296) | [+] ny(1216)
    float* loss_acc = (float*)ws;
    int*   counts   = (int*)  (ws + 4);
    float* sums     = (float*)(ws + 1024);
    float* means    = (float*)(ws + 1024 + 311296);
    float* ny       = (float*)(ws + 1024 + 622592);

    hipMemsetAsync(ws, 0, 1024, stream);                       // zero loss_acc + counts
    k_counts<<<dim3(9, B), 256, 0, stream>>>(target, counts);  // 9*2048 = HW
    k_sums<<<dim3(C, B, 2), 256, 0, stream>>>(fS, fT, target, sums);
    k_means<<<B * K, 256, 0, stream>>>(sums, counts, means, ny);
    k_loss<<<dim3(HW / 128, B), 512, 0, stream>>>(fS, fT, target, means, ny, loss_acc);
    k_final<<<1, 1, 0, stream>>>(loss_acc, out);
}